// Round 6
// baseline (1028.572 us; speedup 1.0000x reference)
//
#include <hip/hip_runtime.h>
#include <math.h>

#define CCH 256
#define NB 2
#define HEADS 64
// Schraudolph-in-MFMA: q scaled by 1024*0.5*log2(e); QK accumulator C-init = magic.
#define QK_SCALE (0.72134752f * 1024.0f)
#define SCH_MAGIC 15316.0f   // 15360 - 44 (centers the +-3% secant error)

typedef _Float16 f16;
typedef _Float16 f16x8 __attribute__((ext_vector_type(8)));
typedef _Float16 f16x4 __attribute__((ext_vector_type(4)));
typedef float f32x4 __attribute__((ext_vector_type(4)));

// ---------------- workspace layout ----------------
static const size_t OFF_POOLED = 0;     // float offsets
static const size_t OFF_DSACC  = 2048;
// f16 region (element offsets from byte 10240)
static const size_t H_Q   = 0;          // [n][256][L], scaled by QK_SCALE
static const size_t H_K   = 2785280;    // [n][h][M][4]  (per-head contiguous)
static const size_t H_V   = 5636096;    // [n][h][4][M]  (per-head contiguous)
static const size_t H_ATT = 8486912;    // [n][L][256]
static const size_t H_SPT = 11272192;   // sp transposed [n][l][256]
static const size_t H_IVT = 14057472;   // inv transposed
static const size_t H_W   = 16842752;   // Wq,Wk,Wv,Wo f16, 262144 each

static const size_t DS_OUT_OFF = 2785280;

__device__ __forceinline__ void lvl_tables(int lvl, int& L, int& M, size_t& qo, size_t& kvo) {
    const int Ls[4] = {4096, 1024, 256, 64};
    const size_t qoff[4] = {0, 2097152, 2621440, 2752512};
    const size_t kvoff[4] = {0, 2113536, 2654208, 2801664};
    L = Ls[lvl]; M = L + 32; qo = qoff[lvl]; kvo = kvoff[lvl];
}

struct P12 { const float* a[12]; };   // sp0..3, iv0..3, ds0..3

// ================= PREP: transposes + weight convert + pooled + dsacc zero
__global__ __launch_bounds__(256)
void prep_kernel(P12 ptrs, const float* __restrict__ Wq, const float* __restrict__ Wk,
                 const float* __restrict__ Wv, const float* __restrict__ Wo,
                 f16* __restrict__ WF, f16* __restrict__ spT, f16* __restrict__ ivT,
                 float* __restrict__ pooled, float* __restrict__ dsacc) {
    int id = blockIdx.x;
    if (id < 5440) {
        __shared__ float tile[32][33];
        int x = id % 170, rest = id / 170;
        int y = rest & 7, z = rest >> 3;
        int lvl, xl;
        if (x < 128) { lvl = 0; xl = x; }
        else if (x < 160) { lvl = 1; xl = x - 128; }
        else if (x < 168) { lvl = 2; xl = x - 160; }
        else { lvl = 3; xl = x - 168; }
        int L, M; size_t qo, kvo;
        lvl_tables(lvl, L, M, qo, kvo);
        int src = z >> 1, n = z & 1;
        const float* X = ptrs.a[src * 4 + lvl];
        f16* XT = (src == 0 ? spT : ivT) + qo;
        int c0 = y * 32, l0 = xl * 32;
        int tx = threadIdx.x & 31, ty = threadIdx.x >> 5;
        #pragma unroll
        for (int k = 0; k < 4; k++) {
            int c = c0 + ty + k * 8;
            tile[ty + k * 8][tx] = X[((size_t)n * CCH + c) * L + l0 + tx];
        }
        __syncthreads();
        #pragma unroll
        for (int k = 0; k < 4; k++) {
            int l = l0 + ty + k * 8;
            XT[((size_t)n * L + l) * CCH + c0 + tx] = (f16)tile[tx][ty + k * 8];
        }
    } else if (id < 6464) {
        int wI = id - 5440;
        int x = wI & 255, setId = wI >> 8;
        const float* src = (setId == 0) ? Wq : (setId == 1) ? Wk : (setId == 2) ? Wv : Wo;
        size_t i = ((size_t)x * 256 + threadIdx.x) * 4;
        float4 v = *(const float4*)(src + i);
        f16x4 o;
        o[0] = (f16)v.x; o[1] = (f16)v.y; o[2] = (f16)v.z; o[3] = (f16)v.w;
        *(f16x4*)(WF + (size_t)setId * 262144 + i) = o;
    } else {
        if (id == 6464) {   // zero dsacc (attn accumulates into it later)
            dsacc[threadIdx.x] = 0.f;
            dsacc[threadIdx.x + 256] = 0.f;
        }
        int lin = (id - 6464) * 4 + (threadIdx.x >> 6);
        int c = lin & 255, n = (lin >> 8) & 1, lvl = lin >> 9;
        int t = threadIdx.x & 63;
        const float* d = ptrs.a[8 + lvl];
        int L = 4096 >> (2 * lvl);
        const float* p = d + ((size_t)n * CCH + c) * L;
        float s = 0.f;
        for (int i = t; i < L; i += 64) s += p[i];
        #pragma unroll
        for (int off = 32; off > 0; off >>= 1) s += __shfl_down(s, off);
        if (t == 0) pooled[(lvl * NB + n) * CCH + c] = s / (float)L;
    }
}

// ================= MID: dstok + convqkv fused =============================
__global__ __launch_bounds__(256)
void mid_kernel(const f16* __restrict__ spT, const f16* __restrict__ ivT,
                const f16* __restrict__ WF,
                const float* __restrict__ bq, const float* __restrict__ bk,
                const float* __restrict__ bv,
                f16* __restrict__ qF, f16* __restrict__ kF, f16* __restrict__ vF,
                const float* __restrict__ Wdsk, const float* __restrict__ bdsk,
                const float* __restrict__ Wdsv, const float* __restrict__ bdsv,
                const float* __restrict__ ds_gate, const float* __restrict__ pooled) {
    int id = blockIdx.x;
    if (id >= 1032) {
        int dI = id - 1032;
        int bx = dI & 63, lvl = dI >> 6;
        int t = threadIdx.x;
        int j = bx * 128 + (t >> 1);
        int half = t & 1;
        const float4* wk = (const float4*)(Wdsk + ((size_t)lvl * 8192 + j) * CCH) + half * 32;
        const float4* wv = (const float4*)(Wdsv + ((size_t)lvl * 8192 + j) * CCH) + half * 32;
        const float4* p0 = (const float4*)(pooled + (size_t)(lvl * NB + 0) * CCH) + half * 32;
        const float4* p1 = (const float4*)(pooled + (size_t)(lvl * NB + 1) * CCH) + half * 32;
        float ak0 = 0.f, ak1 = 0.f, av0 = 0.f, av1 = 0.f;
        #pragma unroll 8
        for (int c4 = 0; c4 < 32; c4++) {
            float4 a = wk[c4], b = wv[c4], pa = p0[c4], pb = p1[c4];
            ak0 += a.x * pa.x + a.y * pa.y + a.z * pa.z + a.w * pa.w;
            ak1 += a.x * pb.x + a.y * pb.y + a.z * pb.z + a.w * pb.w;
            av0 += b.x * pa.x + b.y * pa.y + b.z * pa.z + b.w * pa.w;
            av1 += b.x * pb.x + b.y * pb.y + b.z * pb.z + b.w * pb.w;
        }
        ak0 += __shfl_xor(ak0, 1); ak1 += __shfl_xor(ak1, 1);
        av0 += __shfl_xor(av0, 1); av1 += __shfl_xor(av1, 1);
        if (half) return;
        float bk_ = bdsk[lvl * 8192 + j], bv_ = bdsv[lvl * 8192 + j];
        float gate = 1.f / (1.f + __expf(-ds_gate[lvl]));
        ak0 += bk_; ak1 += bk_;
        av0 = (av0 + bv_) * gate; av1 = (av1 + bv_) * gate;
        int o = j >> 5, tk = j & 31;
        int L, M; size_t qo, kvo;
        lvl_tables(lvl, L, M, qo, kvo);
        int hh = o >> 2, dd = o & 3;
        kF[kvo + ((size_t)(0 * 64 + hh)) * (4 * (size_t)M) + (size_t)(L + tk) * 4 + dd] = (f16)ak0;
        kF[kvo + ((size_t)(1 * 64 + hh)) * (4 * (size_t)M) + (size_t)(L + tk) * 4 + dd] = (f16)ak1;
        vF[kvo + ((size_t)(0 * 64 + hh)) * (4 * (size_t)M) + (size_t)dd * M + (L + tk)] = (f16)av0;
        vF[kvo + ((size_t)(1 * 64 + hh)) * (4 * (size_t)M) + (size_t)dd * M + (L + tk)] = (f16)av1;
        return;
    }
    // ---- convqkv ----
    int x = id % 43, rest = id / 43;
    int yb = rest % 12, n = rest / 12;
    int lvl, xl;
    if (x < 32) { lvl = 0; xl = x; }
    else if (x < 40) { lvl = 1; xl = x - 32; }
    else if (x < 42) { lvl = 2; xl = x - 40; }
    else { lvl = 3; xl = x - 42; }
    int L, M; size_t qo, kvo;
    lvl_tables(lvl, L, M, qo, kvo);
    const int type = yb >> 2;
    const int ob = (yb & 3) * 64;
    const int t = threadIdx.x, w = t >> 6, lane = t & 63;
    const int quad = lane >> 4, n16 = lane & 15;
    const int l0w = xl * 128 + w * 32;
    if (l0w >= L) return;

    const f16* XT = ((type == 0) ? spT : ivT) + qo;
    const f16* Wf = WF + (size_t)type * 262144 + (size_t)lvl * 65536;
    const float* bias = ((type == 0) ? bq : (type == 1) ? bk : bv) + lvl * 256;

    f32x4 acc[4][2];
    #pragma unroll
    for (int f = 0; f < 4; f++)
        #pragma unroll
        for (int g = 0; g < 2; g++) { acc[f][g][0]=0.f; acc[f][g][1]=0.f; acc[f][g][2]=0.f; acc[f][g][3]=0.f; }

    const f16* xp = XT + ((size_t)n * L + l0w + n16) * CCH + quad * 8;
    const f16* wp = Wf + ((size_t)(ob + n16)) * CCH + quad * 8;

    #pragma unroll
    for (int c0 = 0; c0 < 256; c0 += 32) {
        f16x8 af[4], bf[2];
        #pragma unroll
        for (int f = 0; f < 4; f++) af[f] = *(const f16x8*)(wp + (size_t)f * 16 * CCH + c0);
        #pragma unroll
        for (int g = 0; g < 2; g++) bf[g] = *(const f16x8*)(xp + (size_t)g * 16 * CCH + c0);
        #pragma unroll
        for (int f = 0; f < 4; f++)
            #pragma unroll
            for (int g = 0; g < 2; g++)
                acc[f][g] = __builtin_amdgcn_mfma_f32_16x16x32_f16(af[f], bf[g], acc[f][g], 0, 0, 0);
    }

    #pragma unroll
    for (int f = 0; f < 4; f++) {
        #pragma unroll
        for (int g = 0; g < 2; g++) {
            int lloc = l0w + g * 16 + n16;
            float vals[4];
            #pragma unroll
            for (int r = 0; r < 4; r++)
                vals[r] = acc[f][g][r] + bias[ob + f * 16 + quad * 4 + r];
            if (type == 0) {
                #pragma unroll
                for (int r = 0; r < 4; r++)
                    qF[qo + ((size_t)n * CCH + ob + f * 16 + quad * 4 + r) * (size_t)L + lloc] =
                        (f16)(vals[r] * QK_SCALE);
            } else if (type == 1) {
                f16x4 pk;
                #pragma unroll
                for (int r = 0; r < 4; r++) pk[r] = (f16)vals[r];
                int hh = (ob + f * 16 + quad * 4) >> 2;
                *(f16x4*)(kF + kvo + ((size_t)(n * 64 + hh)) * (4 * (size_t)M) + (size_t)lloc * 4) = pk;
            } else {
                int hh = (ob + f * 16 + quad * 4) >> 2;
                f16* vdst = vF + kvo + ((size_t)(n * 64 + hh)) * (4 * (size_t)M) + lloc;
                #pragma unroll
                for (int r = 0; r < 4; r++)
                    vdst[(size_t)r * M] = (f16)vals[r];
            }
        }
    }
}

// ================= ATTENTION ==============================================
// Key-split across waves (R5's depth-2 pipeline spilled to scratch -> 2GB
// traffic; reverted). Block = 64 q-rows (4 tiles); its 4 waves process
// DISJOINT quarter-ranges of the key stream with R3's exact per-wave code
// (acc is linear in keys -> partials add). A 16KB LDS reduction + 1 barrier
// combines; wave w runs the unchanged epilogue for tile w. Per-row load
// traffic identical to R3; TLP 4x (10880 fine blocks); all levels fast-path.
__global__ __launch_bounds__(256, 6)
void attn_all_kernel(const f16* __restrict__ qBase, const f16* __restrict__ kBase,
                     const f16* __restrict__ vBase, f16* __restrict__ attBase,
                     float* __restrict__ dsacc) {
    int x = blockIdx.x, lvl, xl;
    if (x < 64) { lvl = 0; xl = x; }
    else if (x < 80) { lvl = 1; xl = x - 64; }
    else if (x < 84) { lvl = 2; xl = x - 80; }
    else { lvl = 3; xl = 0; }
    int L, M; size_t qo, kvo;
    lvl_tables(lvl, L, M, qo, kvo);
    const f16* qb = qBase + qo;
    f16* attT = attBase + qo;

    const int h = blockIdx.y, b = blockIdx.z;
    const int t = threadIdx.x, w = t >> 6, lane = t & 63;
    const int quad = lane >> 4, n16 = lane & 15;
    const size_t qbase = ((size_t)b * CCH + h * 4) * (size_t)L;
    const int mperm = ((n16 & 12) << 1) + (n16 & 3);  // (n16>>2)*8 + (n16&3)
    const int bt = xl * 4;                            // first 16-row tile of block

    // per-head K/V bases
    const f16* kh = kBase + kvo + ((size_t)(b * 64 + h)) * (4 * (size_t)M);
    const f16* vh = vBase + kvo + ((size_t)(b * 64 + h)) * (4 * (size_t)M);
    const f16* kpm = kh + (size_t)mperm * 4;
    const f16* vpm = vh + (size_t)(n16 & 3) * M + quad * 8;
    const bool vlane = (n16 < 4);

    f16x4 qf[4];
    f32x4 acc[4];
    #pragma unroll
    for (int i = 0; i < 4; i++) {
        #pragma unroll
        for (int e = 0; e < 4; e++) qf[i][e] = (f16)0.f;
        acc[i][0] = 0.f; acc[i][1] = 0.f; acc[i][2] = 0.f; acc[i][3] = 0.f;
    }

    f32x4 magic;
    magic[0] = SCH_MAGIC; magic[1] = SCH_MAGIC; magic[2] = SCH_MAGIC; magic[3] = SCH_MAGIC;

    f16x8 vcon0, vconL;   // B-cols for n16>=4 lanes: main chunks / token chunk
    {
        f16 c0 = (f16)((n16 == 4) ? 1.f : 0.f);
        f16 cL = (f16)((n16 == 4 || n16 == 5) ? 1.f : 0.f);
        #pragma unroll
        for (int e = 0; e < 8; e++) { vcon0[e] = c0; vconL[e] = cL; }
    }

    // q fragments for ALL 4 tiles of the block (all waves identical; L%64==0
    // for every level so all tiles are in-range -> no generic path needed)
    if (quad == 0) {
        #pragma unroll
        for (int i = 0; i < 4; i++) {
            int l = (bt + i) * 16 + n16;
            #pragma unroll
            for (int d = 0; d < 4; d++) qf[i][d] = qb[qbase + (size_t)d * L + l];
        }
    }

#define LOADKV(m0_, ka_, kb_, vf_)                                                      \
    do {                                                                                \
        ka_ = *(const f16x4*)(kpm + (size_t)(m0_) * 4);                                 \
        kb_ = *(const f16x4*)(kpm + (size_t)(m0_) * 4 + 16);                            \
        vf_ = *(const f16x8*)(vpm + (m0_));                                             \
    } while (0)

#define COMPUTE32(ka_, kb_, vfl_, vcon_)                                                \
    do {                                                                                \
        f16x8 vf = vlane ? (vfl_) : (vcon_);                                            \
        f32x4 s[4][2];                                                                  \
        __builtin_amdgcn_s_setprio(1);                                                  \
        _Pragma("unroll")                                                               \
        for (int j = 0; j < 4; j++) {                                                   \
            s[j][0] = __builtin_amdgcn_mfma_f32_16x16x16f16((ka_), qf[j], magic, 0, 0, 0);  \
            s[j][1] = __builtin_amdgcn_mfma_f32_16x16x16f16((kb_), qf[j], magic, 0, 0, 0); \
        }                                                                               \
        _Pragma("unroll")                                                               \
        for (int j = 0; j < 4; j++) {                                                   \
            union { unsigned u[4]; f16x8 hh; } Wu;                                      \
            Wu.u[0] = ((unsigned)(int)s[j][0][0]) | (((unsigned)(int)s[j][0][1]) << 16); \
            Wu.u[1] = ((unsigned)(int)s[j][0][2]) | (((unsigned)(int)s[j][0][3]) << 16); \
            Wu.u[2] = ((unsigned)(int)s[j][1][0]) | (((unsigned)(int)s[j][1][1]) << 16); \
            Wu.u[3] = ((unsigned)(int)s[j][1][2]) | (((unsigned)(int)s[j][1][3]) << 16); \
            acc[j] = __builtin_amdgcn_mfma_f32_16x16x32_f16(Wu.hh, vf, acc[j], 0, 0, 0); \
        }                                                                               \
        __builtin_amdgcn_s_setprio(0);                                                  \
    } while (0)

    // per-wave chunk range: wave w owns chunks [c0, c1) of nch = M/32
    const int nch = M >> 5;
    const int cbase = nch >> 2, crem = nch & 3;
    const int c0 = w * cbase + (w < crem ? w : crem);
    const int c1 = c0 + cbase + (w < crem ? 1 : 0);
    int m0 = c0 << 5;
    const int mend = c1 << 5;

    {
        f16x4 kaA, kbA, kaB, kbB;
        f16x8 vA, vB;
        LOADKV(m0, kaA, kbA, vA);   // harmless over-read if range empty (stays in workspace)
        for (; m0 + 64 <= mend; m0 += 64) {
            LOADKV(m0 + 32, kaB, kbB, vB);
            COMPUTE32(kaA, kbA, vA, (m0 >= L) ? vconL : vcon0);
            LOADKV(m0 + 64, kaA, kbA, vA);   // last iter over-reads next wave's chunk (valid mem)
            COMPUTE32(kaB, kbB, vB, (m0 + 32 >= L) ? vconL : vcon0);
        }
        if (m0 < mend)
            COMPUTE32(kaA, kbA, vA, (m0 >= L) ? vconL : vcon0);
    }
#undef LOADKV
#undef COMPUTE32

    // ---- combine partial accumulators across waves (16 KB LDS) ----
    __shared__ float comb[4][4][4][64];   // [wave][tile][r][lane]
    #pragma unroll
    for (int i = 0; i < 4; i++)
        #pragma unroll
        for (int r = 0; r < 4; r++)
            comb[w][i][r][lane] = acc[i][r];
    __syncthreads();

    float a4[4];
    #pragma unroll
    for (int r = 0; r < 4; r++)
        a4[r] = comb[0][w][r][lane] + comb[1][w][r][lane] + comb[2][w][r][lane] + comb[3][w][r][lane];

    // epilogue for tile (bt + w): col n16 in {d0..d3, den, dst}, rows l = quad*4+r
    const int tl0 = (bt + w) * 16;
    float dsr = 0.f;
    #pragma unroll
    for (int r = 0; r < 4; r++) {
        float den = __shfl(a4[r], (lane & 48) | 4, 64);
        float rcp = 1.f / den;
        int l = tl0 + quad * 4 + r;
        if (n16 < 4)
            attT[((size_t)b * L + l) * CCH + h * 4 + n16] = (f16)(a4[r] * rcp);
        if (n16 == 5) dsr += a4[r] * rcp;
    }
    dsr += __shfl_xor(dsr, 16, 64);
    dsr += __shfl_xor(dsr, 32, 64);
    if (n16 == 5 && quad == 0) atomicAdd(dsacc + (size_t)lvl * 128 + (size_t)b * 64 + h, dsr);
}

// ================= o-conv (fp32 out + residual) + finalize ================
__global__ __launch_bounds__(256)
void convo_kernel(const f16* __restrict__ attT, const f16* __restrict__ WF,
                  const float* __restrict__ bo, const float* __restrict__ s0,
                  const float* __restrict__ s1, const float* __restrict__ s2,
                  const float* __restrict__ s3, float* __restrict__ out,
                  const float* __restrict__ dsacc) {
    if (blockIdx.x == 0 && blockIdx.y == 0 && blockIdx.z == 0 && threadIdx.x < 64) {
        int tt = threadIdx.x;
        #pragma unroll
        for (int i = 0; i < 8; i++) {
            float v = dsacc[i * 64 + tt];
            #pragma unroll
            for (int off = 32; off > 0; off >>= 1) v += __shfl_down(v, off);
            if (tt == 0) {
                int lv = i >> 1;
                out[DS_OUT_OFF + i] = v / (float)(HEADS * (4096 >> (2 * lv)));
            }
        }
    }
    int x = blockIdx.x, lvl, xl;
    if (x < 32) { lvl = 0; xl = x; }
    else if (x < 40) { lvl = 1; xl = x - 32; }
    else if (x < 42) { lvl = 2; xl = x - 40; }
    else { lvl = 3; xl = x - 42; }
    int L, M; size_t qo, kvo;
    lvl_tables(lvl, L, M, qo, kvo);
    const float* resid = (lvl == 0) ? s0 : (lvl == 1) ? s1 : (lvl == 2) ? s2 : s3;
    const int ob = blockIdx.y * 64;
    const int n = blockIdx.z;
    const int t = threadIdx.x, w = t >> 6, lane = t & 63;
    const int quad = lane >> 4, n16 = lane & 15;
    const int l0w = xl * 128 + w * 32;
    if (l0w >= L) return;

    const f16* Wf = WF + 3 * 262144 + (size_t)lvl * 65536;
    const float* bias = bo + lvl * 256;

    f32x4 acc[4][2];
    #pragma unroll
    for (int f = 0; f < 4; f++)
        #pragma unroll
        for (int g = 0; g < 2; g++) { acc[f][g][0]=0.f; acc[f][g][1]=0.f; acc[f][g][2]=0.f; acc[f][g][3]=0.f; }

    const f16* xp = attT + qo + ((size_t)n * L + l0w + n16) * CCH + quad * 8;
    const f16* wp = Wf + ((size_t)(ob + n16)) * CCH + quad * 8;

    #pragma unroll
    for (int c0 = 0; c0 < 256; c0 += 32) {
        f16x8 af[4], bf[2];
        #pragma unroll
        for (int f = 0; f < 4; f++) af[f] = *(const f16x8*)(wp + (size_t)f * 16 * CCH + c0);
        #pragma unroll
        for (int g = 0; g < 2; g++) bf[g] = *(const f16x8*)(xp + (size_t)g * 16 * CCH + c0);
        #pragma unroll
        for (int f = 0; f < 4; f++)
            #pragma unroll
            for (int g = 0; g < 2; g++)
                acc[f][g] = __builtin_amdgcn_mfma_f32_16x16x32_f16(af[f], bf[g], acc[f][g], 0, 0, 0);
    }

    #pragma unroll
    for (int f = 0; f < 4; f++) {
        #pragma unroll
        for (int g = 0; g < 2; g++) {
            int lloc = l0w + g * 16 + n16;
            #pragma unroll
            for (int r = 0; r < 4; r++) {
                size_t idx = qo + ((size_t)n * CCH + ob + f * 16 + quad * 4 + r) * (size_t)L + lloc;
                out[idx] = acc[f][g][r] + bias[ob + f * 16 + quad * 4 + r] + resid[idx - qo];
            }
        }
    }
}

extern "C" void kernel_launch(void* const* d_in, const int* in_sizes, int n_in,
                              void* d_out, int out_size, void* d_ws, size_t ws_size,
                              hipStream_t stream) {
    const float* sp[4] = {(const float*)d_in[0], (const float*)d_in[1], (const float*)d_in[2], (const float*)d_in[3]};
    const float* iv[4] = {(const float*)d_in[4], (const float*)d_in[5], (const float*)d_in[6], (const float*)d_in[7]};
    const float* dd[4] = {(const float*)d_in[8], (const float*)d_in[9], (const float*)d_in[10], (const float*)d_in[11]};
    const float* Wq = (const float*)d_in[12];
    const float* bq = (const float*)d_in[13];
    const float* Wk = (const float*)d_in[14];
    const float* bk = (const float*)d_in[15];
    const float* Wv = (const float*)d_in[16];
    const float* bv = (const float*)d_in[17];
    const float* Wo = (const float*)d_in[18];
    const float* bo = (const float*)d_in[19];
    const float* Wdsk = (const float*)d_in[20];
    const float* bdsk = (const float*)d_in[21];
    const float* Wdsv = (const float*)d_in[22];
    const float* bdsv = (const float*)d_in[23];
    const float* gate = (const float*)d_in[24];

    float* ws = (float*)d_ws;
    float* pooled = ws + OFF_POOLED;
    float* dsacc = ws + OFF_DSACC;
    f16* hb = (f16*)((char*)d_ws + 10240);
    f16* qF   = hb + H_Q;
    f16* kF   = hb + H_K;
    f16* vF   = hb + H_V;
    f16* attF = hb + H_ATT;
    f16* spT  = hb + H_SPT;
    f16* ivT  = hb + H_IVT;
    f16* WF   = hb + H_W;
    float* out = (float*)d_out;

    P12 ptrs;
    for (int i = 0; i < 4; i++) { ptrs.a[i] = sp[i]; ptrs.a[4 + i] = iv[i]; ptrs.a[8 + i] = dd[i]; }

    prep_kernel<<<dim3(6976), 256, 0, stream>>>(ptrs, Wq, Wk, Wv, Wo, WF, spT, ivT, pooled, dsacc);

    mid_kernel<<<dim3(1288), 256, 0, stream>>>(spT, ivT, WF, bq, bk, bv, qF, kF, vF,
                                               Wdsk, bdsk, Wdsv, bdsv, gate, pooled);

    attn_all_kernel<<<dim3(85, 64, 2), 256, 0, stream>>>(qF, kF, vF, attF, dsacc);

    convo_kernel<<<dim3(43, 4, 2), 256, 0, stream>>>(attF, WF, bo, sp[0], sp[1], sp[2], sp[3],
                                                     out, dsacc);
}

// Round 7
// 472.317 us; speedup vs baseline: 2.1777x; 2.1777x over previous
//
#include <hip/hip_runtime.h>
#include <math.h>

#define CCH 256
#define NB 2
#define HEADS 64
// Schraudolph-in-MFMA: q scaled by 1024*0.5*log2(e); QK accumulator C-init = magic.
#define QK_SCALE (0.72134752f * 1024.0f)
#define SCH_MAGIC 15316.0f   // 15360 - 44 (centers the +-3% secant error)

typedef _Float16 f16;
typedef _Float16 f16x8 __attribute__((ext_vector_type(8)));
typedef _Float16 f16x4 __attribute__((ext_vector_type(4)));
typedef float f32x4 __attribute__((ext_vector_type(4)));

// ---------------- workspace layout ----------------
static const size_t OFF_POOLED = 0;     // float offsets
static const size_t OFF_DSACC  = 2048;
// f16 region (element offsets from byte 10240)
static const size_t H_Q   = 0;          // [n][256][L], scaled by QK_SCALE
static const size_t H_K   = 2785280;    // [n][h][M][4]  (per-head contiguous)
static const size_t H_V   = 5636096;    // [n][h][4][M]  (per-head contiguous)
static const size_t H_ATT = 8486912;    // [n][L][256]
static const size_t H_SPT = 11272192;   // sp transposed [n][l][256]
static const size_t H_IVT = 14057472;   // inv transposed
static const size_t H_W   = 16842752;   // Wq,Wk,Wv,Wo f16, 262144 each

static const size_t DS_OUT_OFF = 2785280;

__device__ __forceinline__ void lvl_tables(int lvl, int& L, int& M, size_t& qo, size_t& kvo) {
    const int Ls[4] = {4096, 1024, 256, 64};
    const size_t qoff[4] = {0, 2097152, 2621440, 2752512};
    const size_t kvoff[4] = {0, 2113536, 2654208, 2801664};
    L = Ls[lvl]; M = L + 32; qo = qoff[lvl]; kvo = kvoff[lvl];
}

struct P12 { const float* a[12]; };   // sp0..3, iv0..3, ds0..3

// ================= PREP: transposes + weight convert + pooled + dsacc zero
__global__ __launch_bounds__(256)
void prep_kernel(P12 ptrs, const float* __restrict__ Wq, const float* __restrict__ Wk,
                 const float* __restrict__ Wv, const float* __restrict__ Wo,
                 f16* __restrict__ WF, f16* __restrict__ spT, f16* __restrict__ ivT,
                 float* __restrict__ pooled, float* __restrict__ dsacc) {
    int id = blockIdx.x;
    if (id < 5440) {
        __shared__ float tile[32][33];
        int x = id % 170, rest = id / 170;
        int y = rest & 7, z = rest >> 3;
        int lvl, xl;
        if (x < 128) { lvl = 0; xl = x; }
        else if (x < 160) { lvl = 1; xl = x - 128; }
        else if (x < 168) { lvl = 2; xl = x - 160; }
        else { lvl = 3; xl = x - 168; }
        int L, M; size_t qo, kvo;
        lvl_tables(lvl, L, M, qo, kvo);
        int src = z >> 1, n = z & 1;
        const float* X = ptrs.a[src * 4 + lvl];
        f16* XT = (src == 0 ? spT : ivT) + qo;
        int c0 = y * 32, l0 = xl * 32;
        int tx = threadIdx.x & 31, ty = threadIdx.x >> 5;
        #pragma unroll
        for (int k = 0; k < 4; k++) {
            int c = c0 + ty + k * 8;
            tile[ty + k * 8][tx] = X[((size_t)n * CCH + c) * L + l0 + tx];
        }
        __syncthreads();
        #pragma unroll
        for (int k = 0; k < 4; k++) {
            int l = l0 + ty + k * 8;
            XT[((size_t)n * L + l) * CCH + c0 + tx] = (f16)tile[tx][ty + k * 8];
        }
    } else if (id < 6464) {
        int wI = id - 5440;
        int x = wI & 255, setId = wI >> 8;
        const float* src = (setId == 0) ? Wq : (setId == 1) ? Wk : (setId == 2) ? Wv : Wo;
        size_t i = ((size_t)x * 256 + threadIdx.x) * 4;
        float4 v = *(const float4*)(src + i);
        f16x4 o;
        o[0] = (f16)v.x; o[1] = (f16)v.y; o[2] = (f16)v.z; o[3] = (f16)v.w;
        *(f16x4*)(WF + (size_t)setId * 262144 + i) = o;
    } else {
        if (id == 6464) {   // zero dsacc (attn accumulates into it later)
            dsacc[threadIdx.x] = 0.f;
            dsacc[threadIdx.x + 256] = 0.f;
        }
        int lin = (id - 6464) * 4 + (threadIdx.x >> 6);
        int c = lin & 255, n = (lin >> 8) & 1, lvl = lin >> 9;
        int t = threadIdx.x & 63;
        const float* d = ptrs.a[8 + lvl];
        int L = 4096 >> (2 * lvl);
        const float* p = d + ((size_t)n * CCH + c) * L;
        float s = 0.f;
        for (int i = t; i < L; i += 64) s += p[i];
        #pragma unroll
        for (int off = 32; off > 0; off >>= 1) s += __shfl_down(s, off);
        if (t == 0) pooled[(lvl * NB + n) * CCH + c] = s / (float)L;
    }
}

// ================= MID: dstok + convqkv fused =============================
__global__ __launch_bounds__(256)
void mid_kernel(const f16* __restrict__ spT, const f16* __restrict__ ivT,
                const f16* __restrict__ WF,
                const float* __restrict__ bq, const float* __restrict__ bk,
                const float* __restrict__ bv,
                f16* __restrict__ qF, f16* __restrict__ kF, f16* __restrict__ vF,
                const float* __restrict__ Wdsk, const float* __restrict__ bdsk,
                const float* __restrict__ Wdsv, const float* __restrict__ bdsv,
                const float* __restrict__ ds_gate, const float* __restrict__ pooled) {
    int id = blockIdx.x;
    if (id >= 1032) {
        int dI = id - 1032;
        int bx = dI & 63, lvl = dI >> 6;
        int t = threadIdx.x;
        int j = bx * 128 + (t >> 1);
        int half = t & 1;
        const float4* wk = (const float4*)(Wdsk + ((size_t)lvl * 8192 + j) * CCH) + half * 32;
        const float4* wv = (const float4*)(Wdsv + ((size_t)lvl * 8192 + j) * CCH) + half * 32;
        const float4* p0 = (const float4*)(pooled + (size_t)(lvl * NB + 0) * CCH) + half * 32;
        const float4* p1 = (const float4*)(pooled + (size_t)(lvl * NB + 1) * CCH) + half * 32;
        float ak0 = 0.f, ak1 = 0.f, av0 = 0.f, av1 = 0.f;
        #pragma unroll 8
        for (int c4 = 0; c4 < 32; c4++) {
            float4 a = wk[c4], b = wv[c4], pa = p0[c4], pb = p1[c4];
            ak0 += a.x * pa.x + a.y * pa.y + a.z * pa.z + a.w * pa.w;
            ak1 += a.x * pb.x + a.y * pb.y + a.z * pb.z + a.w * pb.w;
            av0 += b.x * pa.x + b.y * pa.y + b.z * pa.z + b.w * pa.w;
            av1 += b.x * pb.x + b.y * pb.y + b.z * pb.z + b.w * pb.w;
        }
        ak0 += __shfl_xor(ak0, 1); ak1 += __shfl_xor(ak1, 1);
        av0 += __shfl_xor(av0, 1); av1 += __shfl_xor(av1, 1);
        if (half) return;
        float bk_ = bdsk[lvl * 8192 + j], bv_ = bdsv[lvl * 8192 + j];
        float gate = 1.f / (1.f + __expf(-ds_gate[lvl]));
        ak0 += bk_; ak1 += bk_;
        av0 = (av0 + bv_) * gate; av1 = (av1 + bv_) * gate;
        int o = j >> 5, tk = j & 31;
        int L, M; size_t qo, kvo;
        lvl_tables(lvl, L, M, qo, kvo);
        int hh = o >> 2, dd = o & 3;
        kF[kvo + ((size_t)(0 * 64 + hh)) * (4 * (size_t)M) + (size_t)(L + tk) * 4 + dd] = (f16)ak0;
        kF[kvo + ((size_t)(1 * 64 + hh)) * (4 * (size_t)M) + (size_t)(L + tk) * 4 + dd] = (f16)ak1;
        vF[kvo + ((size_t)(0 * 64 + hh)) * (4 * (size_t)M) + (size_t)dd * M + (L + tk)] = (f16)av0;
        vF[kvo + ((size_t)(1 * 64 + hh)) * (4 * (size_t)M) + (size_t)dd * M + (L + tk)] = (f16)av1;
        return;
    }
    // ---- convqkv ----
    int x = id % 43, rest = id / 43;
    int yb = rest % 12, n = rest / 12;
    int lvl, xl;
    if (x < 32) { lvl = 0; xl = x; }
    else if (x < 40) { lvl = 1; xl = x - 32; }
    else if (x < 42) { lvl = 2; xl = x - 40; }
    else { lvl = 3; xl = x - 42; }
    int L, M; size_t qo, kvo;
    lvl_tables(lvl, L, M, qo, kvo);
    const int type = yb >> 2;
    const int ob = (yb & 3) * 64;
    const int t = threadIdx.x, w = t >> 6, lane = t & 63;
    const int quad = lane >> 4, n16 = lane & 15;
    const int l0w = xl * 128 + w * 32;
    if (l0w >= L) return;

    const f16* XT = ((type == 0) ? spT : ivT) + qo;
    const f16* Wf = WF + (size_t)type * 262144 + (size_t)lvl * 65536;
    const float* bias = ((type == 0) ? bq : (type == 1) ? bk : bv) + lvl * 256;

    f32x4 acc[4][2];
    #pragma unroll
    for (int f = 0; f < 4; f++)
        #pragma unroll
        for (int g = 0; g < 2; g++) { acc[f][g][0]=0.f; acc[f][g][1]=0.f; acc[f][g][2]=0.f; acc[f][g][3]=0.f; }

    const f16* xp = XT + ((size_t)n * L + l0w + n16) * CCH + quad * 8;
    const f16* wp = Wf + ((size_t)(ob + n16)) * CCH + quad * 8;

    #pragma unroll
    for (int c0 = 0; c0 < 256; c0 += 32) {
        f16x8 af[4], bf[2];
        #pragma unroll
        for (int f = 0; f < 4; f++) af[f] = *(const f16x8*)(wp + (size_t)f * 16 * CCH + c0);
        #pragma unroll
        for (int g = 0; g < 2; g++) bf[g] = *(const f16x8*)(xp + (size_t)g * 16 * CCH + c0);
        #pragma unroll
        for (int f = 0; f < 4; f++)
            #pragma unroll
            for (int g = 0; g < 2; g++)
                acc[f][g] = __builtin_amdgcn_mfma_f32_16x16x32_f16(af[f], bf[g], acc[f][g], 0, 0, 0);
    }

    #pragma unroll
    for (int f = 0; f < 4; f++) {
        #pragma unroll
        for (int g = 0; g < 2; g++) {
            int lloc = l0w + g * 16 + n16;
            float vals[4];
            #pragma unroll
            for (int r = 0; r < 4; r++)
                vals[r] = acc[f][g][r] + bias[ob + f * 16 + quad * 4 + r];
            if (type == 0) {
                #pragma unroll
                for (int r = 0; r < 4; r++)
                    qF[qo + ((size_t)n * CCH + ob + f * 16 + quad * 4 + r) * (size_t)L + lloc] =
                        (f16)(vals[r] * QK_SCALE);
            } else if (type == 1) {
                f16x4 pk;
                #pragma unroll
                for (int r = 0; r < 4; r++) pk[r] = (f16)vals[r];
                int hh = (ob + f * 16 + quad * 4) >> 2;
                *(f16x4*)(kF + kvo + ((size_t)(n * 64 + hh)) * (4 * (size_t)M) + (size_t)lloc * 4) = pk;
            } else {
                int hh = (ob + f * 16 + quad * 4) >> 2;
                f16* vdst = vF + kvo + ((size_t)(n * 64 + hh)) * (4 * (size_t)M) + lloc;
                #pragma unroll
                for (int r = 0; r < 4; r++)
                    vdst[(size_t)r * M] = (f16)vals[r];
            }
        }
    }
}

// ================= ATTENTION ==============================================
// EXACT R3 inner structure (verified 215us, 40 VGPR, no scratch; R5/R6's
// restructurings both spilled -> 1.4+ GB scratch traffic and regressed).
// Changes vs R3 are OUTSIDE the loop only:
//  - xbase arg: lvl0 launches as its own dispatch of exactly 2048 blocks
//    (= 8 blocks/CU = one full residency round, uniform duration -> no
//    quantized drain tail that held R3 at 48% occupancy); lvl1-3 follow
//    as a second short dispatch.
//  - s_setprio(1/0) around the MFMA cluster (T5; present in R4/R6 builds
//    with no allocation pathology).
__global__ __launch_bounds__(256, 6)
void attn_all_kernel(const f16* __restrict__ qBase, const f16* __restrict__ kBase,
                     const f16* __restrict__ vBase, f16* __restrict__ attBase,
                     float* __restrict__ dsacc, int xbase) {
    int x = blockIdx.x + xbase, lvl, xl;
    if (x < 16) { lvl = 0; xl = x; }
    else if (x < 20) { lvl = 1; xl = x - 16; }
    else if (x < 21) { lvl = 2; xl = 0; }
    else { lvl = 3; xl = 0; }
    int L, M; size_t qo, kvo;
    lvl_tables(lvl, L, M, qo, kvo);
    const f16* qb = qBase + qo;
    f16* attT = attBase + qo;

    const int h = blockIdx.y, b = blockIdx.z;
    const int t = threadIdx.x, w = t >> 6, lane = t & 63;
    const int quad = lane >> 4, n16 = lane & 15;
    const size_t qbase = ((size_t)b * CCH + h * 4) * (size_t)L;
    const int mperm = ((n16 & 12) << 1) + (n16 & 3);  // (n16>>2)*8 + (n16&3)
    const int base_tile = xl * 16;

    // per-head K/V bases
    const f16* kh = kBase + kvo + ((size_t)(b * 64 + h)) * (4 * (size_t)M);
    const f16* vh = vBase + kvo + ((size_t)(b * 64 + h)) * (4 * (size_t)M);
    const f16* kpm = kh + (size_t)mperm * 4;
    const f16* vpm = vh + (size_t)(n16 & 3) * M + quad * 8;
    const bool vlane = (n16 < 4);

    f16x4 qf[4];
    f32x4 acc[4];
    #pragma unroll
    for (int i = 0; i < 4; i++) {
        #pragma unroll
        for (int e = 0; e < 4; e++) qf[i][e] = (f16)0.f;
        acc[i][0] = 0.f; acc[i][1] = 0.f; acc[i][2] = 0.f; acc[i][3] = 0.f;
    }

    f32x4 magic;
    magic[0] = SCH_MAGIC; magic[1] = SCH_MAGIC; magic[2] = SCH_MAGIC; magic[3] = SCH_MAGIC;

    f16x8 vcon0, vconL;   // B-cols for n16>=4 lanes: main chunks / token chunk
    {
        f16 c0 = (f16)((n16 == 4) ? 1.f : 0.f);
        f16 cL = (f16)((n16 == 4 || n16 == 5) ? 1.f : 0.f);
        #pragma unroll
        for (int e = 0; e < 8; e++) { vcon0[e] = c0; vconL[e] = cL; }
    }

// load one 32-key sub-chunk's operands into registers
#define LOADKV(m0_, ka_, kb_, vf_)                                                      \
    do {                                                                                \
        ka_ = *(const f16x4*)(kpm + (size_t)(m0_) * 4);                                 \
        kb_ = *(const f16x4*)(kpm + (size_t)(m0_) * 4 + 16);                            \
        vf_ = *(const f16x8*)(vpm + (m0_));                                             \
    } while (0)

// compute one 32-key sub-chunk from registers (identical math to R3)
#define COMPUTE32(ka_, kb_, vfl_, vcon_)                                                \
    do {                                                                                \
        f16x8 vf = vlane ? (vfl_) : (vcon_);                                            \
        f32x4 s[4][2];                                                                  \
        __builtin_amdgcn_s_setprio(1);                                                  \
        _Pragma("unroll")                                                               \
        for (int j = 0; j < 4; j++) {                                                   \
            s[j][0] = __builtin_amdgcn_mfma_f32_16x16x16f16((ka_), qf[j], magic, 0, 0, 0);  \
            s[j][1] = __builtin_amdgcn_mfma_f32_16x16x16f16((kb_), qf[j], magic, 0, 0, 0); \
        }                                                                               \
        _Pragma("unroll")                                                               \
        for (int j = 0; j < 4; j++) {                                                   \
            union { unsigned u[4]; f16x8 hh; } Wu;                                      \
            Wu.u[0] = ((unsigned)(int)s[j][0][0]) | (((unsigned)(int)s[j][0][1]) << 16); \
            Wu.u[1] = ((unsigned)(int)s[j][0][2]) | (((unsigned)(int)s[j][0][3]) << 16); \
            Wu.u[2] = ((unsigned)(int)s[j][1][0]) | (((unsigned)(int)s[j][1][1]) << 16); \
            Wu.u[3] = ((unsigned)(int)s[j][1][2]) | (((unsigned)(int)s[j][1][3]) << 16); \
            acc[j] = __builtin_amdgcn_mfma_f32_16x16x32_f16(Wu.hh, vf, acc[j], 0, 0, 0); \
        }                                                                               \
        __builtin_amdgcn_s_setprio(0);                                                  \
    } while (0)

    if (base_tile * 16 + 256 <= L) {
        // ---- fast path: all 4 tiles valid, L % 64 == 0 (lvl 0,1,2) ----
        if (quad == 0) {
            #pragma unroll
            for (int i = 0; i < 4; i++) {
                int l = (base_tile + i * 4 + w) * 16 + n16;
                #pragma unroll
                for (int d = 0; d < 4; d++) qf[i][d] = qb[qbase + (size_t)d * L + l];
            }
        }
        f16x4 kaA, kbA, kaB, kbB;
        f16x8 vA, vB;
        LOADKV(0, kaA, kbA, vA);
        for (int m0 = 0; m0 < L; m0 += 64) {
            LOADKV(m0 + 32, kaB, kbB, vB);
            COMPUTE32(kaA, kbA, vA, vcon0);
            LOADKV(m0 + 64, kaA, kbA, vA);   // final iter prefetches token chunk [L, L+32)
            COMPUTE32(kaB, kbB, vB, vcon0);
        }
        COMPUTE32(kaA, kbA, vA, vconL);      // token chunk
    } else {
        // ---- generic path (partial blocks: level 3) ----
        bool valid[4];
        #pragma unroll
        for (int i = 0; i < 4; i++) {
            int tl0 = (base_tile + i * 4 + w) * 16;
            valid[i] = (tl0 < L);
            if (valid[i] && quad == 0) {
                int l = tl0 + n16;
                #pragma unroll
                for (int d = 0; d < 4; d++) qf[i][d] = qb[qbase + (size_t)d * L + l];
            }
        }
        for (int m0 = 0; m0 < M; m0 += 32) {
            f16x4 ka = *(const f16x4*)(kpm + (size_t)m0 * 4);
            f16x4 kb2 = *(const f16x4*)(kpm + (size_t)m0 * 4 + 16);
            f16x8 vfl = *(const f16x8*)(vpm + m0);
            f16x8 vf = vlane ? vfl : ((m0 >= L) ? vconL : vcon0);
            f32x4 s[4][2];
            #pragma unroll
            for (int j = 0; j < 4; j++) {
                if (!valid[j]) continue;
                s[j][0] = __builtin_amdgcn_mfma_f32_16x16x16f16(ka, qf[j], magic, 0, 0, 0);
                s[j][1] = __builtin_amdgcn_mfma_f32_16x16x16f16(kb2, qf[j], magic, 0, 0, 0);
            }
            #pragma unroll
            for (int j = 0; j < 4; j++) {
                if (!valid[j]) continue;
                union { unsigned u[4]; f16x8 hh; } Wu;
                Wu.u[0] = ((unsigned)(int)s[j][0][0]) | (((unsigned)(int)s[j][0][1]) << 16);
                Wu.u[1] = ((unsigned)(int)s[j][0][2]) | (((unsigned)(int)s[j][0][3]) << 16);
                Wu.u[2] = ((unsigned)(int)s[j][1][0]) | (((unsigned)(int)s[j][1][1]) << 16);
                Wu.u[3] = ((unsigned)(int)s[j][1][2]) | (((unsigned)(int)s[j][1][3]) << 16);
                acc[j] = __builtin_amdgcn_mfma_f32_16x16x32_f16(Wu.hh, vf, acc[j], 0, 0, 0);
            }
        }
    }
#undef LOADKV
#undef COMPUTE32

    // epilogue: C of PV: col n16 in {d0..d3, den, dst}, rows l = quad*4+r
    float dsr = 0.f;
    #pragma unroll
    for (int i = 0; i < 4; i++) {
        int tl0 = (base_tile + i * 4 + w) * 16;
        if (tl0 >= L) continue;
        #pragma unroll
        for (int r = 0; r < 4; r++) {
            float den = __shfl(acc[i][r], (lane & 48) | 4, 64);
            float rcp = 1.f / den;
            int l = tl0 + quad * 4 + r;
            if (n16 < 4)
                attT[((size_t)b * L + l) * CCH + h * 4 + n16] = (f16)(acc[i][r] * rcp);
            if (n16 == 5) dsr += acc[i][r] * rcp;
        }
    }
    dsr += __shfl_xor(dsr, 16, 64);
    dsr += __shfl_xor(dsr, 32, 64);
    if (n16 == 5 && quad == 0) atomicAdd(dsacc + (size_t)lvl * 128 + (size_t)b * 64 + h, dsr);
}

// ================= o-conv (fp32 out + residual) + finalize ================
__global__ __launch_bounds__(256)
void convo_kernel(const f16* __restrict__ attT, const f16* __restrict__ WF,
                  const float* __restrict__ bo, const float* __restrict__ s0,
                  const float* __restrict__ s1, const float* __restrict__ s2,
                  const float* __restrict__ s3, float* __restrict__ out,
                  const float* __restrict__ dsacc) {
    if (blockIdx.x == 0 && blockIdx.y == 0 && blockIdx.z == 0 && threadIdx.x < 64) {
        int tt = threadIdx.x;
        #pragma unroll
        for (int i = 0; i < 8; i++) {
            float v = dsacc[i * 64 + tt];
            #pragma unroll
            for (int off = 32; off > 0; off >>= 1) v += __shfl_down(v, off);
            if (tt == 0) {
                int lv = i >> 1;
                out[DS_OUT_OFF + i] = v / (float)(HEADS * (4096 >> (2 * lv)));
            }
        }
    }
    int x = blockIdx.x, lvl, xl;
    if (x < 32) { lvl = 0; xl = x; }
    else if (x < 40) { lvl = 1; xl = x - 32; }
    else if (x < 42) { lvl = 2; xl = x - 40; }
    else { lvl = 3; xl = x - 42; }
    int L, M; size_t qo, kvo;
    lvl_tables(lvl, L, M, qo, kvo);
    const float* resid = (lvl == 0) ? s0 : (lvl == 1) ? s1 : (lvl == 2) ? s2 : s3;
    const int ob = blockIdx.y * 64;
    const int n = blockIdx.z;
    const int t = threadIdx.x, w = t >> 6, lane = t & 63;
    const int quad = lane >> 4, n16 = lane & 15;
    const int l0w = xl * 128 + w * 32;
    if (l0w >= L) return;

    const f16* Wf = WF + 3 * 262144 + (size_t)lvl * 65536;
    const float* bias = bo + lvl * 256;

    f32x4 acc[4][2];
    #pragma unroll
    for (int f = 0; f < 4; f++)
        #pragma unroll
        for (int g = 0; g < 2; g++) { acc[f][g][0]=0.f; acc[f][g][1]=0.f; acc[f][g][2]=0.f; acc[f][g][3]=0.f; }

    const f16* xp = attT + qo + ((size_t)n * L + l0w + n16) * CCH + quad * 8;
    const f16* wp = Wf + ((size_t)(ob + n16)) * CCH + quad * 8;

    #pragma unroll
    for (int c0 = 0; c0 < 256; c0 += 32) {
        f16x8 af[4], bf[2];
        #pragma unroll
        for (int f = 0; f < 4; f++) af[f] = *(const f16x8*)(wp + (size_t)f * 16 * CCH + c0);
        #pragma unroll
        for (int g = 0; g < 2; g++) bf[g] = *(const f16x8*)(xp + (size_t)g * 16 * CCH + c0);
        #pragma unroll
        for (int f = 0; f < 4; f++)
            #pragma unroll
            for (int g = 0; g < 2; g++)
                acc[f][g] = __builtin_amdgcn_mfma_f32_16x16x32_f16(af[f], bf[g], acc[f][g], 0, 0, 0);
    }

    #pragma unroll
    for (int f = 0; f < 4; f++) {
        #pragma unroll
        for (int g = 0; g < 2; g++) {
            int lloc = l0w + g * 16 + n16;
            #pragma unroll
            for (int r = 0; r < 4; r++) {
                size_t idx = qo + ((size_t)n * CCH + ob + f * 16 + quad * 4 + r) * (size_t)L + lloc;
                out[idx] = acc[f][g][r] + bias[ob + f * 16 + quad * 4 + r] + resid[idx - qo];
            }
        }
    }
}

extern "C" void kernel_launch(void* const* d_in, const int* in_sizes, int n_in,
                              void* d_out, int out_size, void* d_ws, size_t ws_size,
                              hipStream_t stream) {
    const float* sp[4] = {(const float*)d_in[0], (const float*)d_in[1], (const float*)d_in[2], (const float*)d_in[3]};
    const float* iv[4] = {(const float*)d_in[4], (const float*)d_in[5], (const float*)d_in[6], (const float*)d_in[7]};
    const float* dd[4] = {(const float*)d_in[8], (const float*)d_in[9], (const float*)d_in[10], (const float*)d_in[11]};
    const float* Wq = (const float*)d_in[12];
    const float* bq = (const float*)d_in[13];
    const float* Wk = (const float*)d_in[14];
    const float* bk = (const float*)d_in[15];
    const float* Wv = (const float*)d_in[16];
    const float* bv = (const float*)d_in[17];
    const float* Wo = (const float*)d_in[18];
    const float* bo = (const float*)d_in[19];
    const float* Wdsk = (const float*)d_in[20];
    const float* bdsk = (const float*)d_in[21];
    const float* Wdsv = (const float*)d_in[22];
    const float* bdsv = (const float*)d_in[23];
    const float* gate = (const float*)d_in[24];

    float* ws = (float*)d_ws;
    float* pooled = ws + OFF_POOLED;
    float* dsacc = ws + OFF_DSACC;
    f16* hb = (f16*)((char*)d_ws + 10240);
    f16* qF   = hb + H_Q;
    f16* kF   = hb + H_K;
    f16* vF   = hb + H_V;
    f16* attF = hb + H_ATT;
    f16* spT  = hb + H_SPT;
    f16* ivT  = hb + H_IVT;
    f16* WF   = hb + H_W;
    float* out = (float*)d_out;

    P12 ptrs;
    for (int i = 0; i < 4; i++) { ptrs.a[i] = sp[i]; ptrs.a[4 + i] = iv[i]; ptrs.a[8 + i] = dd[i]; }

    prep_kernel<<<dim3(6976), 256, 0, stream>>>(ptrs, Wq, Wk, Wv, Wo, WF, spT, ivT, pooled, dsacc);

    mid_kernel<<<dim3(1288), 256, 0, stream>>>(spT, ivT, WF, bq, bk, bv, qF, kF, vF,
                                               Wdsk, bdsk, Wdsv, bdsv, gate, pooled);

    // lvl0 alone: exactly 2048 blocks = 8 blocks/CU = one full, uniform round
    attn_all_kernel<<<dim3(16, 64, 2), 256, 0, stream>>>(qF, kF, vF, attF, dsacc, 0);
    // lvl1-3: short blocks
    attn_all_kernel<<<dim3(6, 64, 2), 256, 0, stream>>>(qF, kF, vF, attF, dsacc, 16);

    convo_kernel<<<dim3(43, 4, 2), 256, 0, stream>>>(attF, WF, bo, sp[0], sp[1], sp[2], sp[3],
                                                     out, dsacc);
}

// Round 8
// 463.813 us; speedup vs baseline: 2.2176x; 1.0183x over previous
//
#include <hip/hip_runtime.h>
#include <math.h>

#define CCH 256
#define NB 2
#define HEADS 64
// Schraudolph-in-MFMA: q scaled by 1024*0.5*log2(e); QK accumulator C-init = magic.
#define QK_SCALE (0.72134752f * 1024.0f)
#define SCH_MAGIC 15316.0f   // 15360 - 44 (centers the +-3% secant error)

typedef _Float16 f16;
typedef _Float16 f16x8 __attribute__((ext_vector_type(8)));
typedef _Float16 f16x4 __attribute__((ext_vector_type(4)));
typedef float f32x4 __attribute__((ext_vector_type(4)));

// ---------------- workspace layout ----------------
static const size_t OFF_POOLED = 0;     // float offsets
static const size_t OFF_DSACC  = 2048;
// f16 region (element offsets from byte 10240)
static const size_t H_Q   = 0;          // [n][256][L], scaled by QK_SCALE
static const size_t H_K   = 2785280;    // [n][h][M][4]  (per-head contiguous)
static const size_t H_V   = 5636096;    // [n][h][4][M]  (per-head contiguous)
static const size_t H_ATT = 8486912;    // [n][L][256]
static const size_t H_SPT = 11272192;   // sp transposed [n][l][256]
static const size_t H_IVT = 14057472;   // inv transposed
static const size_t H_W   = 16842752;   // Wq,Wk,Wv,Wo f16, 262144 each

static const size_t DS_OUT_OFF = 2785280;

__device__ __forceinline__ void lvl_tables(int lvl, int& L, int& M, size_t& qo, size_t& kvo) {
    const int Ls[4] = {4096, 1024, 256, 64};
    const size_t qoff[4] = {0, 2097152, 2621440, 2752512};
    const size_t kvoff[4] = {0, 2113536, 2654208, 2801664};
    L = Ls[lvl]; M = L + 32; qo = qoff[lvl]; kvo = kvoff[lvl];
}

struct P12 { const float* a[12]; };   // sp0..3, iv0..3, ds0..3

// ================= PREP: transposes + weight convert + pooled + dsacc zero
__global__ __launch_bounds__(256)
void prep_kernel(P12 ptrs, const float* __restrict__ Wq, const float* __restrict__ Wk,
                 const float* __restrict__ Wv, const float* __restrict__ Wo,
                 f16* __restrict__ WF, f16* __restrict__ spT, f16* __restrict__ ivT,
                 float* __restrict__ pooled, float* __restrict__ dsacc) {
    int id = blockIdx.x;
    if (id < 5440) {
        __shared__ float tile[32][33];
        int x = id % 170, rest = id / 170;
        int y = rest & 7, z = rest >> 3;
        int lvl, xl;
        if (x < 128) { lvl = 0; xl = x; }
        else if (x < 160) { lvl = 1; xl = x - 128; }
        else if (x < 168) { lvl = 2; xl = x - 160; }
        else { lvl = 3; xl = x - 168; }
        int L, M; size_t qo, kvo;
        lvl_tables(lvl, L, M, qo, kvo);
        int src = z >> 1, n = z & 1;
        const float* X = ptrs.a[src * 4 + lvl];
        f16* XT = (src == 0 ? spT : ivT) + qo;
        int c0 = y * 32, l0 = xl * 32;
        int tx = threadIdx.x & 31, ty = threadIdx.x >> 5;
        #pragma unroll
        for (int k = 0; k < 4; k++) {
            int c = c0 + ty + k * 8;
            tile[ty + k * 8][tx] = X[((size_t)n * CCH + c) * L + l0 + tx];
        }
        __syncthreads();
        #pragma unroll
        for (int k = 0; k < 4; k++) {
            int l = l0 + ty + k * 8;
            XT[((size_t)n * L + l) * CCH + c0 + tx] = (f16)tile[tx][ty + k * 8];
        }
    } else if (id < 6464) {
        int wI = id - 5440;
        int x = wI & 255, setId = wI >> 8;
        const float* src = (setId == 0) ? Wq : (setId == 1) ? Wk : (setId == 2) ? Wv : Wo;
        size_t i = ((size_t)x * 256 + threadIdx.x) * 4;
        float4 v = *(const float4*)(src + i);
        f16x4 o;
        o[0] = (f16)v.x; o[1] = (f16)v.y; o[2] = (f16)v.z; o[3] = (f16)v.w;
        *(f16x4*)(WF + (size_t)setId * 262144 + i) = o;
    } else {
        if (id == 6464) {   // zero dsacc (attn accumulates into it later)
            dsacc[threadIdx.x] = 0.f;
            dsacc[threadIdx.x + 256] = 0.f;
        }
        int lin = (id - 6464) * 4 + (threadIdx.x >> 6);
        int c = lin & 255, n = (lin >> 8) & 1, lvl = lin >> 9;
        int t = threadIdx.x & 63;
        const float* d = ptrs.a[8 + lvl];
        int L = 4096 >> (2 * lvl);
        const float* p = d + ((size_t)n * CCH + c) * L;
        float s = 0.f;
        for (int i = t; i < L; i += 64) s += p[i];
        #pragma unroll
        for (int off = 32; off > 0; off >>= 1) s += __shfl_down(s, off);
        if (t == 0) pooled[(lvl * NB + n) * CCH + c] = s / (float)L;
    }
}

// ================= MID: dstok + convqkv fused =============================
// convqkv re-tiled for TLP (R7 diagnosis: 1032 blocks = 4/CU was the same
// latency-starved regime attn had pre-R3). Now 16 rows/wave, 64 rows/block:
// 85 x 12 x 2 = 2040 blocks = 8/CU. Same inner math, g-loop dropped.
// grid flat 2296: [0,2040) convqkv; [2040,2296) dstok (64 x 4)
__global__ __launch_bounds__(256)
void mid_kernel(const f16* __restrict__ spT, const f16* __restrict__ ivT,
                const f16* __restrict__ WF,
                const float* __restrict__ bq, const float* __restrict__ bk,
                const float* __restrict__ bv,
                f16* __restrict__ qF, f16* __restrict__ kF, f16* __restrict__ vF,
                const float* __restrict__ Wdsk, const float* __restrict__ bdsk,
                const float* __restrict__ Wdsv, const float* __restrict__ bdsv,
                const float* __restrict__ ds_gate, const float* __restrict__ pooled) {
    int id = blockIdx.x;
    if (id >= 2040) {
        int dI = id - 2040;
        int bx = dI & 63, lvl = dI >> 6;
        int t = threadIdx.x;
        int j = bx * 128 + (t >> 1);
        int half = t & 1;
        const float4* wk = (const float4*)(Wdsk + ((size_t)lvl * 8192 + j) * CCH) + half * 32;
        const float4* wv = (const float4*)(Wdsv + ((size_t)lvl * 8192 + j) * CCH) + half * 32;
        const float4* p0 = (const float4*)(pooled + (size_t)(lvl * NB + 0) * CCH) + half * 32;
        const float4* p1 = (const float4*)(pooled + (size_t)(lvl * NB + 1) * CCH) + half * 32;
        float ak0 = 0.f, ak1 = 0.f, av0 = 0.f, av1 = 0.f;
        #pragma unroll 8
        for (int c4 = 0; c4 < 32; c4++) {
            float4 a = wk[c4], b = wv[c4], pa = p0[c4], pb = p1[c4];
            ak0 += a.x * pa.x + a.y * pa.y + a.z * pa.z + a.w * pa.w;
            ak1 += a.x * pb.x + a.y * pb.y + a.z * pb.z + a.w * pb.w;
            av0 += b.x * pa.x + b.y * pa.y + b.z * pa.z + b.w * pa.w;
            av1 += b.x * pb.x + b.y * pb.y + b.z * pb.z + b.w * pb.w;
        }
        ak0 += __shfl_xor(ak0, 1); ak1 += __shfl_xor(ak1, 1);
        av0 += __shfl_xor(av0, 1); av1 += __shfl_xor(av1, 1);
        if (half) return;
        float bk_ = bdsk[lvl * 8192 + j], bv_ = bdsv[lvl * 8192 + j];
        float gate = 1.f / (1.f + __expf(-ds_gate[lvl]));
        ak0 += bk_; ak1 += bk_;
        av0 = (av0 + bv_) * gate; av1 = (av1 + bv_) * gate;
        int o = j >> 5, tk = j & 31;
        int L, M; size_t qo, kvo;
        lvl_tables(lvl, L, M, qo, kvo);
        int hh = o >> 2, dd = o & 3;
        kF[kvo + ((size_t)(0 * 64 + hh)) * (4 * (size_t)M) + (size_t)(L + tk) * 4 + dd] = (f16)ak0;
        kF[kvo + ((size_t)(1 * 64 + hh)) * (4 * (size_t)M) + (size_t)(L + tk) * 4 + dd] = (f16)ak1;
        vF[kvo + ((size_t)(0 * 64 + hh)) * (4 * (size_t)M) + (size_t)dd * M + (L + tk)] = (f16)av0;
        vF[kvo + ((size_t)(1 * 64 + hh)) * (4 * (size_t)M) + (size_t)dd * M + (L + tk)] = (f16)av1;
        return;
    }
    // ---- convqkv: 16 rows/wave, 64 rows/block ----
    int x = id % 85, rest = id / 85;
    int yb = rest % 12, n = rest / 12;
    int lvl, xl;
    if (x < 64) { lvl = 0; xl = x; }
    else if (x < 80) { lvl = 1; xl = x - 64; }
    else if (x < 84) { lvl = 2; xl = x - 80; }
    else { lvl = 3; xl = 0; }
    int L, M; size_t qo, kvo;
    lvl_tables(lvl, L, M, qo, kvo);
    const int type = yb >> 2;
    const int ob = (yb & 3) * 64;
    const int t = threadIdx.x, w = t >> 6, lane = t & 63;
    const int quad = lane >> 4, n16 = lane & 15;
    const int l0w = xl * 64 + w * 16;   // always < L (all L % 64 == 0)

    const f16* XT = ((type == 0) ? spT : ivT) + qo;
    const f16* Wf = WF + (size_t)type * 262144 + (size_t)lvl * 65536;
    const float* bias = ((type == 0) ? bq : (type == 1) ? bk : bv) + lvl * 256;

    f32x4 acc[4];
    #pragma unroll
    for (int f = 0; f < 4; f++) { acc[f][0]=0.f; acc[f][1]=0.f; acc[f][2]=0.f; acc[f][3]=0.f; }

    const f16* xp = XT + ((size_t)n * L + l0w + n16) * CCH + quad * 8;
    const f16* wp = Wf + ((size_t)(ob + n16)) * CCH + quad * 8;

    #pragma unroll
    for (int c0 = 0; c0 < 256; c0 += 32) {
        f16x8 af[4], bf;
        #pragma unroll
        for (int f = 0; f < 4; f++) af[f] = *(const f16x8*)(wp + (size_t)f * 16 * CCH + c0);
        bf = *(const f16x8*)(xp + c0);
        #pragma unroll
        for (int f = 0; f < 4; f++)
            acc[f] = __builtin_amdgcn_mfma_f32_16x16x32_f16(af[f], bf, acc[f], 0, 0, 0);
    }

    const int lloc = l0w + n16;
    #pragma unroll
    for (int f = 0; f < 4; f++) {
        float vals[4];
        #pragma unroll
        for (int r = 0; r < 4; r++)
            vals[r] = acc[f][r] + bias[ob + f * 16 + quad * 4 + r];
        if (type == 0) {
            #pragma unroll
            for (int r = 0; r < 4; r++)
                qF[qo + ((size_t)n * CCH + ob + f * 16 + quad * 4 + r) * (size_t)L + lloc] =
                    (f16)(vals[r] * QK_SCALE);
        } else if (type == 1) {
            f16x4 pk;
            #pragma unroll
            for (int r = 0; r < 4; r++) pk[r] = (f16)vals[r];
            int hh = (ob + f * 16 + quad * 4) >> 2;
            *(f16x4*)(kF + kvo + ((size_t)(n * 64 + hh)) * (4 * (size_t)M) + (size_t)lloc * 4) = pk;
        } else {
            int hh = (ob + f * 16 + quad * 4) >> 2;
            f16* vdst = vF + kvo + ((size_t)(n * 64 + hh)) * (4 * (size_t)M) + lloc;
            #pragma unroll
            for (int r = 0; r < 4; r++)
                vdst[(size_t)r * M] = (f16)vals[r];
        }
    }
}

// ================= ATTENTION ==============================================
// EXACT R7 kernel (verified 187.5us lvl0 dispatch; do NOT restructure the
// inner loop — R5/R6 restructurings both spilled to scratch and regressed).
__global__ __launch_bounds__(256, 6)
void attn_all_kernel(const f16* __restrict__ qBase, const f16* __restrict__ kBase,
                     const f16* __restrict__ vBase, f16* __restrict__ attBase,
                     float* __restrict__ dsacc, int xbase) {
    int x = blockIdx.x + xbase, lvl, xl;
    if (x < 16) { lvl = 0; xl = x; }
    else if (x < 20) { lvl = 1; xl = x - 16; }
    else if (x < 21) { lvl = 2; xl = 0; }
    else { lvl = 3; xl = 0; }
    int L, M; size_t qo, kvo;
    lvl_tables(lvl, L, M, qo, kvo);
    const f16* qb = qBase + qo;
    f16* attT = attBase + qo;

    const int h = blockIdx.y, b = blockIdx.z;
    const int t = threadIdx.x, w = t >> 6, lane = t & 63;
    const int quad = lane >> 4, n16 = lane & 15;
    const size_t qbase = ((size_t)b * CCH + h * 4) * (size_t)L;
    const int mperm = ((n16 & 12) << 1) + (n16 & 3);  // (n16>>2)*8 + (n16&3)
    const int base_tile = xl * 16;

    // per-head K/V bases
    const f16* kh = kBase + kvo + ((size_t)(b * 64 + h)) * (4 * (size_t)M);
    const f16* vh = vBase + kvo + ((size_t)(b * 64 + h)) * (4 * (size_t)M);
    const f16* kpm = kh + (size_t)mperm * 4;
    const f16* vpm = vh + (size_t)(n16 & 3) * M + quad * 8;
    const bool vlane = (n16 < 4);

    f16x4 qf[4];
    f32x4 acc[4];
    #pragma unroll
    for (int i = 0; i < 4; i++) {
        #pragma unroll
        for (int e = 0; e < 4; e++) qf[i][e] = (f16)0.f;
        acc[i][0] = 0.f; acc[i][1] = 0.f; acc[i][2] = 0.f; acc[i][3] = 0.f;
    }

    f32x4 magic;
    magic[0] = SCH_MAGIC; magic[1] = SCH_MAGIC; magic[2] = SCH_MAGIC; magic[3] = SCH_MAGIC;

    f16x8 vcon0, vconL;   // B-cols for n16>=4 lanes: main chunks / token chunk
    {
        f16 c0 = (f16)((n16 == 4) ? 1.f : 0.f);
        f16 cL = (f16)((n16 == 4 || n16 == 5) ? 1.f : 0.f);
        #pragma unroll
        for (int e = 0; e < 8; e++) { vcon0[e] = c0; vconL[e] = cL; }
    }

// load one 32-key sub-chunk's operands into registers
#define LOADKV(m0_, ka_, kb_, vf_)                                                      \
    do {                                                                                \
        ka_ = *(const f16x4*)(kpm + (size_t)(m0_) * 4);                                 \
        kb_ = *(const f16x4*)(kpm + (size_t)(m0_) * 4 + 16);                            \
        vf_ = *(const f16x8*)(vpm + (m0_));                                             \
    } while (0)

// compute one 32-key sub-chunk from registers (identical math to R3)
#define COMPUTE32(ka_, kb_, vfl_, vcon_)                                                \
    do {                                                                                \
        f16x8 vf = vlane ? (vfl_) : (vcon_);                                            \
        f32x4 s[4][2];                                                                  \
        __builtin_amdgcn_s_setprio(1);                                                  \
        _Pragma("unroll")                                                               \
        for (int j = 0; j < 4; j++) {                                                   \
            s[j][0] = __builtin_amdgcn_mfma_f32_16x16x16f16((ka_), qf[j], magic, 0, 0, 0);  \
            s[j][1] = __builtin_amdgcn_mfma_f32_16x16x16f16((kb_), qf[j], magic, 0, 0, 0); \
        }                                                                               \
        _Pragma("unroll")                                                               \
        for (int j = 0; j < 4; j++) {                                                   \
            union { unsigned u[4]; f16x8 hh; } Wu;                                      \
            Wu.u[0] = ((unsigned)(int)s[j][0][0]) | (((unsigned)(int)s[j][0][1]) << 16); \
            Wu.u[1] = ((unsigned)(int)s[j][0][2]) | (((unsigned)(int)s[j][0][3]) << 16); \
            Wu.u[2] = ((unsigned)(int)s[j][1][0]) | (((unsigned)(int)s[j][1][1]) << 16); \
            Wu.u[3] = ((unsigned)(int)s[j][1][2]) | (((unsigned)(int)s[j][1][3]) << 16); \
            acc[j] = __builtin_amdgcn_mfma_f32_16x16x32_f16(Wu.hh, vf, acc[j], 0, 0, 0); \
        }                                                                               \
        __builtin_amdgcn_s_setprio(0);                                                  \
    } while (0)

    if (base_tile * 16 + 256 <= L) {
        // ---- fast path: all 4 tiles valid, L % 64 == 0 (lvl 0,1,2) ----
        if (quad == 0) {
            #pragma unroll
            for (int i = 0; i < 4; i++) {
                int l = (base_tile + i * 4 + w) * 16 + n16;
                #pragma unroll
                for (int d = 0; d < 4; d++) qf[i][d] = qb[qbase + (size_t)d * L + l];
            }
        }
        f16x4 kaA, kbA, kaB, kbB;
        f16x8 vA, vB;
        LOADKV(0, kaA, kbA, vA);
        for (int m0 = 0; m0 < L; m0 += 64) {
            LOADKV(m0 + 32, kaB, kbB, vB);
            COMPUTE32(kaA, kbA, vA, vcon0);
            LOADKV(m0 + 64, kaA, kbA, vA);   // final iter prefetches token chunk [L, L+32)
            COMPUTE32(kaB, kbB, vB, vcon0);
        }
        COMPUTE32(kaA, kbA, vA, vconL);      // token chunk
    } else {
        // ---- generic path (partial blocks: level 3) ----
        bool valid[4];
        #pragma unroll
        for (int i = 0; i < 4; i++) {
            int tl0 = (base_tile + i * 4 + w) * 16;
            valid[i] = (tl0 < L);
            if (valid[i] && quad == 0) {
                int l = tl0 + n16;
                #pragma unroll
                for (int d = 0; d < 4; d++) qf[i][d] = qb[qbase + (size_t)d * L + l];
            }
        }
        for (int m0 = 0; m0 < M; m0 += 32) {
            f16x4 ka = *(const f16x4*)(kpm + (size_t)m0 * 4);
            f16x4 kb2 = *(const f16x4*)(kpm + (size_t)m0 * 4 + 16);
            f16x8 vfl = *(const f16x8*)(vpm + m0);
            f16x8 vf = vlane ? vfl : ((m0 >= L) ? vconL : vcon0);
            f32x4 s[4][2];
            #pragma unroll
            for (int j = 0; j < 4; j++) {
                if (!valid[j]) continue;
                s[j][0] = __builtin_amdgcn_mfma_f32_16x16x16f16(ka, qf[j], magic, 0, 0, 0);
                s[j][1] = __builtin_amdgcn_mfma_f32_16x16x16f16(kb2, qf[j], magic, 0, 0, 0);
            }
            #pragma unroll
            for (int j = 0; j < 4; j++) {
                if (!valid[j]) continue;
                union { unsigned u[4]; f16x8 hh; } Wu;
                Wu.u[0] = ((unsigned)(int)s[j][0][0]) | (((unsigned)(int)s[j][0][1]) << 16);
                Wu.u[1] = ((unsigned)(int)s[j][0][2]) | (((unsigned)(int)s[j][0][3]) << 16);
                Wu.u[2] = ((unsigned)(int)s[j][1][0]) | (((unsigned)(int)s[j][1][1]) << 16);
                Wu.u[3] = ((unsigned)(int)s[j][1][2]) | (((unsigned)(int)s[j][1][3]) << 16);
                acc[j] = __builtin_amdgcn_mfma_f32_16x16x32_f16(Wu.hh, vf, acc[j], 0, 0, 0);
            }
        }
    }
#undef LOADKV
#undef COMPUTE32

    // epilogue: C of PV: col n16 in {d0..d3, den, dst}, rows l = quad*4+r
    float dsr = 0.f;
    #pragma unroll
    for (int i = 0; i < 4; i++) {
        int tl0 = (base_tile + i * 4 + w) * 16;
        if (tl0 >= L) continue;
        #pragma unroll
        for (int r = 0; r < 4; r++) {
            float den = __shfl(acc[i][r], (lane & 48) | 4, 64);
            float rcp = 1.f / den;
            int l = tl0 + quad * 4 + r;
            if (n16 < 4)
                attT[((size_t)b * L + l) * CCH + h * 4 + n16] = (f16)(acc[i][r] * rcp);
            if (n16 == 5) dsr += acc[i][r] * rcp;
        }
    }
    dsr += __shfl_xor(dsr, 16, 64);
    dsr += __shfl_xor(dsr, 32, 64);
    if (n16 == 5 && quad == 0) atomicAdd(dsacc + (size_t)lvl * 128 + (size_t)b * 64 + h, dsr);
}

// ================= o-conv (fp32 out + residual) + finalize ================
// Re-tiled for TLP: was 344 blocks = 1.3/CU (the worst-starved kernel in the
// pipeline). Now 16 rows/wave, 64 rows x 32 outs per block: 85 x 8 x 2 =
// 1360 blocks = 5.3/CU. Same inner math, g-loop dropped, guard gone.
__global__ __launch_bounds__(256)
void convo_kernel(const f16* __restrict__ attT, const f16* __restrict__ WF,
                  const float* __restrict__ bo, const float* __restrict__ s0,
                  const float* __restrict__ s1, const float* __restrict__ s2,
                  const float* __restrict__ s3, float* __restrict__ out,
                  const float* __restrict__ dsacc) {
    if (blockIdx.x == 0 && blockIdx.y == 0 && blockIdx.z == 0 && threadIdx.x < 64) {
        int tt = threadIdx.x;
        #pragma unroll
        for (int i = 0; i < 8; i++) {
            float v = dsacc[i * 64 + tt];
            #pragma unroll
            for (int off = 32; off > 0; off >>= 1) v += __shfl_down(v, off);
            if (tt == 0) {
                int lv = i >> 1;
                out[DS_OUT_OFF + i] = v / (float)(HEADS * (4096 >> (2 * lv)));
            }
        }
    }
    int x = blockIdx.x, lvl, xl;
    if (x < 64) { lvl = 0; xl = x; }
    else if (x < 80) { lvl = 1; xl = x - 64; }
    else if (x < 84) { lvl = 2; xl = x - 80; }
    else { lvl = 3; xl = 0; }
    int L, M; size_t qo, kvo;
    lvl_tables(lvl, L, M, qo, kvo);
    const float* resid = (lvl == 0) ? s0 : (lvl == 1) ? s1 : (lvl == 2) ? s2 : s3;
    const int ob = blockIdx.y * 32;
    const int n = blockIdx.z;
    const int t = threadIdx.x, w = t >> 6, lane = t & 63;
    const int quad = lane >> 4, n16 = lane & 15;
    const int l0w = xl * 64 + w * 16;   // always < L

    const f16* Wf = WF + 3 * 262144 + (size_t)lvl * 65536;
    const float* bias = bo + lvl * 256;

    f32x4 acc[2];
    #pragma unroll
    for (int f = 0; f < 2; f++) { acc[f][0]=0.f; acc[f][1]=0.f; acc[f][2]=0.f; acc[f][3]=0.f; }

    const f16* xp = attT + qo + ((size_t)n * L + l0w + n16) * CCH + quad * 8;
    const f16* wp = Wf + ((size_t)(ob + n16)) * CCH + quad * 8;

    #pragma unroll
    for (int c0 = 0; c0 < 256; c0 += 32) {
        f16x8 af[2], bf;
        #pragma unroll
        for (int f = 0; f < 2; f++) af[f] = *(const f16x8*)(wp + (size_t)f * 16 * CCH + c0);
        bf = *(const f16x8*)(xp + c0);
        #pragma unroll
        for (int f = 0; f < 2; f++)
            acc[f] = __builtin_amdgcn_mfma_f32_16x16x32_f16(af[f], bf, acc[f], 0, 0, 0);
    }

    const int lloc = l0w + n16;
    #pragma unroll
    for (int f = 0; f < 2; f++) {
        #pragma unroll
        for (int r = 0; r < 4; r++) {
            size_t idx = qo + ((size_t)n * CCH + ob + f * 16 + quad * 4 + r) * (size_t)L + lloc;
            out[idx] = acc[f][r] + bias[ob + f * 16 + quad * 4 + r] + resid[idx - qo];
        }
    }
}

extern "C" void kernel_launch(void* const* d_in, const int* in_sizes, int n_in,
                              void* d_out, int out_size, void* d_ws, size_t ws_size,
                              hipStream_t stream) {
    const float* sp[4] = {(const float*)d_in[0], (const float*)d_in[1], (const float*)d_in[2], (const float*)d_in[3]};
    const float* iv[4] = {(const float*)d_in[4], (const float*)d_in[5], (const float*)d_in[6], (const float*)d_in[7]};
    const float* dd[4] = {(const float*)d_in[8], (const float*)d_in[9], (const float*)d_in[10], (const float*)d_in[11]};
    const float* Wq = (const float*)d_in[12];
    const float* bq = (const float*)d_in[13];
    const float* Wk = (const float*)d_in[14];
    const float* bk = (const float*)d_in[15];
    const float* Wv = (const float*)d_in[16];
    const float* bv = (const float*)d_in[17];
    const float* Wo = (const float*)d_in[18];
    const float* bo = (const float*)d_in[19];
    const float* Wdsk = (const float*)d_in[20];
    const float* bdsk = (const float*)d_in[21];
    const float* Wdsv = (const float*)d_in[22];
    const float* bdsv = (const float*)d_in[23];
    const float* gate = (const float*)d_in[24];

    float* ws = (float*)d_ws;
    float* pooled = ws + OFF_POOLED;
    float* dsacc = ws + OFF_DSACC;
    f16* hb = (f16*)((char*)d_ws + 10240);
    f16* qF   = hb + H_Q;
    f16* kF   = hb + H_K;
    f16* vF   = hb + H_V;
    f16* attF = hb + H_ATT;
    f16* spT  = hb + H_SPT;
    f16* ivT  = hb + H_IVT;
    f16* WF   = hb + H_W;
    float* out = (float*)d_out;

    P12 ptrs;
    for (int i = 0; i < 4; i++) { ptrs.a[i] = sp[i]; ptrs.a[4 + i] = iv[i]; ptrs.a[8 + i] = dd[i]; }

    prep_kernel<<<dim3(6976), 256, 0, stream>>>(ptrs, Wq, Wk, Wv, Wo, WF, spT, ivT, pooled, dsacc);

    mid_kernel<<<dim3(2296), 256, 0, stream>>>(spT, ivT, WF, bq, bk, bv, qF, kF, vF,
                                               Wdsk, bdsk, Wdsv, bdsv, gate, pooled);

    // lvl0 alone: exactly 2048 blocks = 8 blocks/CU = one full, uniform round
    attn_all_kernel<<<dim3(16, 64, 2), 256, 0, stream>>>(qF, kF, vF, attF, dsacc, 0);
    // lvl1-3: short blocks
    attn_all_kernel<<<dim3(6, 64, 2), 256, 0, stream>>>(qF, kF, vF, attF, dsacc, 16);

    convo_kernel<<<dim3(85, 8, 2), 256, 0, stream>>>(attF, WF, bo, sp[0], sp[1], sp[2], sp[3],
                                                     out, dsacc);
}